// Round 6
// baseline (233.985 us; speedup 1.0000x reference)
//
#include <hip/hip_runtime.h>
#include <math.h>

#define LL 512
#define EE 1024
#define HH 16
#define DD 64
#define NSX 16               // N*S
#define NT (NSX*LL)          // 8192 tokens
#define NSLE (NT*EE)         // 8388608
// q is pre-scaled by (1/sqrt(512)) * log2(e) so softmax uses native exp2
#define SCALE_Q 0.06375871f

typedef unsigned short u16;
typedef short bf16x8 __attribute__((ext_vector_type(8)));
typedef float f32x4 __attribute__((ext_vector_type(4)));

__device__ inline u16 f2bf(float f) {
  unsigned u = __float_as_uint(f);
  u += 0x7fff + ((u >> 16) & 1);          // RNE
  return (u16)(u >> 16);
}

// direct builtin calls only; ONLY gfx950-verified MFMA shapes (16x16x32)
#define FEXP2(x) __builtin_amdgcn_exp2f(x)
#define MFMA32(a, b, c) __builtin_amdgcn_mfma_f32_16x16x32_bf16((a), (b), (c), 0, 0, 0)

// async 16B global->LDS (wave-uniform LDS base + lane*16 layout)
__device__ inline void gload16(const void* g, void* l) {
  __builtin_amdgcn_global_load_lds(
      (const __attribute__((address_space(1))) unsigned int*)g,
      (__attribute__((address_space(3))) unsigned int*)l, 16, 0, 0);
}

// ---------------- K0: convert weights fp32 -> bf16 ----------------
__global__ void __launch_bounds__(256) convw_kernel(
    const float* __restrict__ Wv, const float* __restrict__ Wk,
    const float* __restrict__ Wq, const float* __restrict__ Wo,
    u16* __restrict__ Wvb, u16* __restrict__ Wkb,
    u16* __restrict__ Wqb, u16* __restrict__ Wob) {
  int i = blockIdx.x * 256 + threadIdx.x;   // quad index
  const float* s; u16* d; int j;
  if (i < 262144) { s = Wo; d = Wob; j = i; }
  else {
    j = i - 262144;
    if (j < 1024)      { s = Wv; d = Wvb; }
    else if (j < 2048) { s = Wk; d = Wkb; j -= 1024; }
    else               { s = Wq; d = Wqb; j -= 2048; }
  }
  float4 f = ((const float4*)s)[j];
  ushort4 o; o.x = f2bf(f.x); o.y = f2bf(f.y); o.z = f2bf(f.z); o.w = f2bf(f.w);
  ((ushort4*)d)[j] = o;
}

// ---------------- K1: projections, CONTIGUOUS-read + LDS staging ----------
// One block = (mat, ns, 16-token tile): stages 16 full rows (64KB fp32) with
// dense coalesced float4 reads (256 thr x 16B, consecutive lanes contiguous;
// rolling 2-deep batches — the structure the compiler respects, r5 lesson),
// converts to bf16 in LDS Xs[16][1032] (+16B pad: fragment reads ~conflict-
// free). W is head-invariant [64][64]: loaded once to regs before the barrier.
// Each wave then computes 4 heads: 2 LDS b128 + 8 MFMA + 4 ushort4 stores per
// head — MFMA orientations and store layouts identical to verified r1/r2 code.
__global__ void __launch_bounds__(256, 4) proj_kernel(
    const float* __restrict__ vals, const float* __restrict__ keys,
    const float* __restrict__ qry,
    const u16* __restrict__ Wvb, const u16* __restrict__ Wkb,
    const u16* __restrict__ Wqb,
    u16* __restrict__ vpT, u16* __restrict__ kp, u16* __restrict__ qp) {
  const int b = blockIdx.x;
  const int tile = b & 31, ns = (b >> 5) & 15, mat = b >> 9;
  const int tid = threadIdx.x;
  const int wid = tid >> 6, lane = tid & 63, quad = lane >> 4, l16 = lane & 15;
  const float* src = (mat == 0 ? vals : mat == 1 ? keys : qry);
  const u16*   W   = (mat == 0 ? Wvb  : mat == 1 ? Wkb  : Wqb);
  u16* dst = (mat == 1 ? kp : qp);
  const float sc = (mat == 2) ? SCALE_Q : 1.f;
  __shared__ u16 Xs[16][1032];          // 16 tokens x 1024 d (+16B pad) 33024 B
  const int t0 = ns*LL + tile*16;
  const float* gbase = src + (size_t)t0*EE;
  // ---- staging prologue: batches 0,1 (rows 0..7), rolling 2-deep ----
  float4 xb0[4], xb1[4];
  #pragma unroll
  for (int k = 0; k < 4; ++k)
    xb0[k] = *(const float4*)&gbase[(size_t)k*EE + tid*4];
  #pragma unroll
  for (int k = 0; k < 4; ++k)
    xb1[k] = *(const float4*)&gbase[(size_t)(4 + k)*EE + tid*4];
  // ---- W fragments: head-invariant, register-resident (overlap staging) ----
  bf16x8 wf[4][2];
  #pragma unroll
  for (int nt = 0; nt < 4; ++nt) {
    wf[nt][0] = *(const bf16x8*)&W[(nt*16 + l16)*DD + quad*8];
    wf[nt][1] = *(const bf16x8*)&W[(nt*16 + l16)*DD + 32 + quad*8];
  }
  #pragma unroll
  for (int bt = 0; bt < 4; ++bt) {
    float4 nx[4];
    if (bt < 2) {
      #pragma unroll
      for (int k = 0; k < 4; ++k)
        nx[k] = *(const float4*)&gbase[(size_t)((bt + 2)*4 + k)*EE + tid*4];
    }
    #pragma unroll
    for (int k = 0; k < 4; ++k) {       // convert batch bt (rows bt*4+k)
      ushort4 o;
      o.x = f2bf(xb0[k].x); o.y = f2bf(xb0[k].y);
      o.z = f2bf(xb0[k].z); o.w = f2bf(xb0[k].w);
      *(ushort4*)&Xs[bt*4 + k][tid*4] = o;
    }
    #pragma unroll
    for (int k = 0; k < 4; ++k) { xb0[k] = xb1[k]; if (bt < 2) xb1[k] = nx[k]; }
  }
  f32x4 z = {0.f, 0.f, 0.f, 0.f};
  __syncthreads();
  // ---- compute: wave handles heads wid*4 .. wid*4+3 ----
  #pragma unroll
  for (int ht = 0; ht < 4; ++ht) {
    const int h = wid*4 + ht;
    bf16x8 af0 = *(const bf16x8*)&Xs[l16][h*DD + quad*8];
    bf16x8 af1 = *(const bf16x8*)&Xs[l16][h*DD + 32 + quad*8];
    if (mat == 0) {
      // acc[nt][r] = out[token = t0+quad*4+r][d = nt*16+l16]
      f32x4 acc[4];
      #pragma unroll
      for (int nt = 0; nt < 4; ++nt) {
        acc[nt] = MFMA32(af0, wf[nt][0], z);
        acc[nt] = MFMA32(af1, wf[nt][1], acc[nt]);
      }
      // transposed store: rows d = nt*16+l16, 4 consecutive tokens as ushort4
      #pragma unroll
      for (int nt = 0; nt < 4; ++nt) {
        ushort4 o;
        o.x = f2bf(acc[nt][0]); o.y = f2bf(acc[nt][1]);
        o.z = f2bf(acc[nt][2]); o.w = f2bf(acc[nt][3]);
        size_t idx = ((size_t)((ns*HH + h)*DD + nt*16 + l16))*LL + tile*16 + quad*4;
        *(ushort4*)&vpT[idx] = o;
      }
    } else {
      // swapped: acc[nt][r] = out[token = t0+l16][d = nt*16+quad*4+r]
      f32x4 acc[4];
      #pragma unroll
      for (int nt = 0; nt < 4; ++nt) {
        acc[nt] = MFMA32(wf[nt][0], af0, z);
        acc[nt] = MFMA32(wf[nt][1], af1, acc[nt]);
      }
      #pragma unroll
      for (int nt = 0; nt < 4; ++nt) {
        ushort4 o;
        o.x = f2bf(acc[nt][0] * sc); o.y = f2bf(acc[nt][1] * sc);
        o.z = f2bf(acc[nt][2] * sc); o.w = f2bf(acc[nt][3] * sc);
        *(ushort4*)&dst[(size_t)(t0 + l16)*EE + h*DD + nt*16 + quad*4] = o;
      }
    }
  }
}

// ---------------- K2: fused column-softmax + attention-out ----------------
// one block per (ns,h): 256 blocks x 1024 threads. K resident in LDS.
// softmax over the QUERY axis: csum_l = sum_q m_q*exp2(e).
// Phase B = r3-verified body (E^T = MFMA(K,Q) -> ushort4 P -> pa/vb MFMA),
// with TRUE V pipelining (T14): chunk-0 V loads issued at kernel start;
// per chunk, next-chunk loads issue BEFORE compute and the reg->LDS write
// lands AFTER compute; one barrier per chunk. vb hoisted out of the qt loop.
__global__ void __launch_bounds__(1024, 4) attn_kernel(
    const u16* __restrict__ qp, const u16* __restrict__ kp,
    const u16* __restrict__ vpT, const int* __restrict__ mask,
    u16* __restrict__ oat) {
  const int b = blockIdx.x;
  const int h = b & 15, ns = b >> 4;
  const int tid = threadIdx.x;
  const int wid = tid >> 6, lane = tid & 63, quad = lane >> 4, l16 = lane & 15;
  __shared__ u16 Ks[LL][72];        // K[l][d]      73728 B
  __shared__ u16 Vt[2][DD][72];     // V^T[d][l64]  18432 B
  __shared__ u16 pt[16][32][40];    // per-wave P   40960 B (phase A: psum f32[16][512])
  __shared__ float csum[LL];        //               2048 B   => 135168 B total
  float* psum = (float*)pt;
  // ---- V chunk-0 prefetch into regs (latency hides under phase A) ----
  const size_t vgbase = ((size_t)((ns*HH + h)*DD))*LL;
  const int vrow = tid >> 4, vseg = (tid & 15) * 4;   // 64 rows x 16 segs of 8B
  ushort4 vreg = *(const ushort4*)&vpT[vgbase + (size_t)vrow*LL + vseg];
  // ---- stage K ----
  const size_t kgbase = ((size_t)(ns*LL))*EE + h*DD;
  for (int i = tid; i < 4096; i += 1024) {          // 512 rows x 8 segs of 16B
    int row = i >> 3, seg = (i & 7) * 8;
    *(bf16x8*)&Ks[row][seg] = *(const bf16x8*)&kp[kgbase + (size_t)row*EE + seg];
  }
  // ---- persistent Q fragments (wave owns 32 q rows) + masks ----
  const int q0 = wid*32;
  bf16x8 qf[2][2];
  float maf[2][4];    // phase A: q = q0+qt*16+quad*4+r
  float mqf[2];       // phase B: q = q0+qt*16+l16 (E^T orientation)
  #pragma unroll
  for (int qt = 0; qt < 2; ++qt) {
    const u16* qrow = qp + ((size_t)(ns*LL + q0 + qt*16 + l16))*EE + h*DD;
    qf[qt][0] = *(const bf16x8*)&qrow[quad*8];
    qf[qt][1] = *(const bf16x8*)&qrow[32 + quad*8];
    #pragma unroll
    for (int r = 0; r < 4; ++r)
      maf[qt][r] = mask[ns*LL + q0 + qt*16 + quad*4 + r] ? 1.f : 0.f;
    mqf[qt] = mask[ns*LL + q0 + qt*16 + l16] ? 1.f : 0.f;
  }
  f32x4 z = {0.f, 0.f, 0.f, 0.f};
  __syncthreads();
  // ---- phase A: column partial sums -> psum[wid][l], then block reduce ----
  for (int lt = 0; lt < 32; ++lt) {
    bf16x8 kf0 = *(const bf16x8*)&Ks[lt*16 + l16][quad*8];
    bf16x8 kf1 = *(const bf16x8*)&Ks[lt*16 + l16][32 + quad*8];
    float part = 0.f;
    #pragma unroll
    for (int qt = 0; qt < 2; ++qt) {
      f32x4 e = MFMA32(qf[qt][0], kf0, z);
      e = MFMA32(qf[qt][1], kf1, e);
      #pragma unroll
      for (int r = 0; r < 4; ++r)
        part += maf[qt][r] * FEXP2(e[r]);     // e row = q(quad*4+r), col = l(l16)
    }
    part += __shfl_xor(part, 16);             // combine 4 quads (same l16)
    part += __shfl_xor(part, 32);
    if (quad == 0) psum[wid*512 + lt*16 + l16] = part;
  }
  __syncthreads();
  if (tid < LL) {
    float s = 0.f;
    #pragma unroll
    for (int w = 0; w < 16; ++w) s += psum[w*512 + tid];
    csum[tid] = (s > 0.f) ? 1.f/s : 0.f;
  }
  __syncthreads();
  // ---- write prefetched chunk 0 into Vt[0] ----
  *(ushort4*)&Vt[0][vrow][vseg] = vreg;
  // ---- phase B: E^T recompute -> P via ushort4 -> PV, V chunks of 64 l ----
  f32x4 acc[4][2] = {{z,z},{z,z},{z,z},{z,z}};   // [dtile][qt]
  for (int lc = 0; lc < 8; ++lc) {               // 8 chunks of 64 l
    // issue NEXT chunk's V loads (regs) before compute — latency hides under it
    ushort4 nreg;
    if (lc < 7)
      nreg = *(const ushort4*)&vpT[vgbase + (size_t)vrow*LL + (lc+1)*64 + vseg];
    __syncthreads();                             // Vt[lc&1] writes now visible
    // E^T + P for 64 l in 4 sub-tiles of 16
    #pragma unroll
    for (int lt2 = 0; lt2 < 4; ++lt2) {
      const int lb = lc*64 + lt2*16;
      bf16x8 kf0 = *(const bf16x8*)&Ks[lb + l16][quad*8];
      bf16x8 kf1 = *(const bf16x8*)&Ks[lb + l16][32 + quad*8];
      float4 cs4 = *(const float4*)&csum[lb + quad*4];   // csum for l=lb+quad*4+r
      #pragma unroll
      for (int qt = 0; qt < 2; ++qt) {
        // E^T: lane holds e[l = lb+quad*4+r][q = q0+qt*16+l16]
        f32x4 e = MFMA32(kf0, qf[qt][0], z);
        e = MFMA32(kf1, qf[qt][1], e);
        const float m = mqf[qt];
        ushort4 o;
        o.x = f2bf(m * cs4.x * FEXP2(e[0]));
        o.y = f2bf(m * cs4.y * FEXP2(e[1]));
        o.z = f2bf(m * cs4.z * FEXP2(e[2]));
        o.w = f2bf(m * cs4.w * FEXP2(e[3]));
        // P[q][l]: row q = qt*16+l16, cols l-rel = (lt2&1)*16 + quad*4 .. +3
        *(ushort4*)&pt[wid][qt*16 + l16][(lt2 & 1)*16 + quad*4] = o;
      }
      // PV for the 32-l half once both sub-tiles of it are in pt
      if (lt2 & 1) {
        bf16x8 vb[4];                            // hoisted out of qt loop
        #pragma unroll
        for (int dt = 0; dt < 4; ++dt)
          vb[dt] = *(const bf16x8*)&Vt[lc & 1][dt*16 + l16]
                                      [(lt2 >> 1)*32 + quad*8];
        #pragma unroll
        for (int qt = 0; qt < 2; ++qt) {
          bf16x8 pa = *(const bf16x8*)&pt[wid][qt*16 + l16][quad*8];
          #pragma unroll
          for (int dt = 0; dt < 4; ++dt)
            acc[dt][qt] = MFMA32(pa, vb[dt], acc[dt][qt]);
        }
      }
    }
    // write NEXT chunk into the other buffer AFTER compute (T14 late write)
    if (lc < 7)
      *(ushort4*)&Vt[(lc+1) & 1][vrow][vseg] = nreg;
  }
  // ---- write out[q][d]: D row = q(quad*4+r), col = d(l16) ----
  #pragma unroll
  for (int qt = 0; qt < 2; ++qt)
    #pragma unroll
    for (int dt = 0; dt < 4; ++dt)
      #pragma unroll
      for (int r = 0; r < 4; ++r)
        oat[((size_t)(ns*LL + q0 + qt*16 + quad*4 + r))*EE + h*DD + dt*16 + l16] =
            f2bf(acc[dt][qt][r]);
}

// ---------------- K4: Y = oat @ Wo^T + bo, m97-style MFMA GEMM --------------
// 128x64 tile, BK=64 -> grid 1024 = 4 blocks/CU. 4 waves as 2x2 over
// (128m x 64n), each computing 64x32. Staging via global_load_lds width=16.
__global__ void __launch_bounds__(256) out_gemm_kernel(
    const u16* __restrict__ A, const u16* __restrict__ Wob,
    const float* __restrict__ bo, float* __restrict__ Y) {
  __shared__ u16 As[128][64];   // [m][k]  16384 B, linear for global_load_lds
  __shared__ u16 Bs[64][64];    // [n][k]   8192 B
  const int b = blockIdx.x;     // 64 mtiles x 16 ntiles
  const int nb = b & 15, mb = b >> 4;
  const int m0 = mb*128, n0 = nb*64;
  const int tid = threadIdx.x;
  const int wid = tid >> 6, lane = tid & 63, quad = lane >> 4, l16 = lane & 15;
  const int wm = (wid >> 1)*64, wn = (wid & 1)*32;   // wave sub-tile 64x32
  const int r0 = tid >> 3, sseg = (tid & 7) * 8;     // staging row/col (u16)
  u16* adst = &As[0][0] + tid*8;                     // lane-linear 16B chunks
  u16* bdst = &Bs[0][0] + tid*8;
  f32x4 z = {0.f, 0.f, 0.f, 0.f};
  f32x4 acc[4][2];
  #pragma unroll
  for (int i = 0; i < 4; ++i)
    #pragma unroll
    for (int j = 0; j < 2; ++j) acc[i][j] = z;
  for (int k0 = 0; k0 < EE; k0 += 64) {
    __syncthreads();                    // previous tile fully consumed
    #pragma unroll
    for (int it = 0; it < 4; ++it)      // A: 128 rows x 64 k
      gload16(&A[(size_t)(m0 + it*32 + r0)*EE + k0 + sseg], adst + it*2048);
    #pragma unroll
    for (int it = 0; it < 2; ++it)      // B: 64 rows x 64 k
      gload16(&Wob[(size_t)(n0 + it*32 + r0)*EE + k0 + sseg], bdst + it*2048);
    __syncthreads();                    // vmcnt(0) drain -> LDS data ready
    #pragma unroll
    for (int kk = 0; kk < 2; ++kk) {
      bf16x8 af[4], bfr[2];
      #pragma unroll
      for (int i = 0; i < 4; ++i)
        af[i] = *(const bf16x8*)&As[wm + i*16 + l16][kk*32 + quad*8];
      #pragma unroll
      for (int j = 0; j < 2; ++j)
        bfr[j] = *(const bf16x8*)&Bs[wn + j*16 + l16][kk*32 + quad*8];
      #pragma unroll
      for (int i = 0; i < 4; ++i)
        #pragma unroll
        for (int j = 0; j < 2; ++j)
          acc[i][j] = MFMA32(af[i], bfr[j], acc[i][j]);
    }
  }
  #pragma unroll
  for (int i = 0; i < 4; ++i)
    #pragma unroll
    for (int j = 0; j < 2; ++j) {
      int col = n0 + wn + j*16 + l16;
      float bias = bo[col];
      #pragma unroll
      for (int r = 0; r < 4; ++r)
        Y[(size_t)(m0 + wm + i*16 + quad*4 + r)*EE + col] = acc[i][j][r] + bias;
    }
}

extern "C" void kernel_launch(void* const* d_in, const int* in_sizes, int n_in,
                              void* d_out, int out_size, void* d_ws, size_t ws_size,
                              hipStream_t stream) {
  const float* values = (const float*)d_in[0];
  const float* keysp  = (const float*)d_in[1];
  const float* query  = (const float*)d_in[2];
  const int*   mask   = (const int*)d_in[3];
  const float* Wv = (const float*)d_in[4];
  const float* Wk = (const float*)d_in[5];
  const float* Wq = (const float*)d_in[6];
  const float* Wo = (const float*)d_in[7];
  const float* bo = (const float*)d_in[8];
  float* Y = (float*)d_out;

  u16* qp  = (u16*)d_ws;
  u16* kp  = qp + NSLE;
  u16* vpT = kp + NSLE;
  u16* oat = vpT + NSLE;
  u16* Wob = oat + NSLE;
  u16* Wvb = Wob + EE*EE;
  u16* Wkb = Wvb + DD*DD;
  u16* Wqb = Wkb + DD*DD;

  convw_kernel<<<1036, 256, 0, stream>>>(Wv, Wk, Wq, Wo, Wvb, Wkb, Wqb, Wob);
  proj_kernel<<<3*NSX*32, 256, 0, stream>>>(values, keysp, query,
                                            Wvb, Wkb, Wqb, vpT, kp, qp);
  attn_kernel<<<NSX*HH, 1024, 0, stream>>>(qp, kp, vpT, mask, oat);
  out_gemm_kernel<<<(NT/128)*(EE/64), 256, 0, stream>>>(oat, Wob, bo, Y);
}